// Round 3
// baseline (627.691 us; speedup 1.0000x reference)
//
#include <hip/hip_runtime.h>
#include <hip/hip_bf16.h>
#include <math.h>

// B=4, S=2048, D=256, H=4, HD=64; keep top-10% per score row.
// thr = v205 + 0.3*(v204 - v205)  (v_k = (k+1)-th largest)

typedef __attribute__((ext_vector_type(8))) short short8;
typedef __attribute__((ext_vector_type(4))) short short4v;
typedef __attribute__((ext_vector_type(8))) _Float16 half8;
typedef __attribute__((ext_vector_type(4))) _Float16 half4;
typedef __attribute__((ext_vector_type(4))) float floatx4;
typedef unsigned short ushort_t;

#define MFMA_BF(a,b,c)  __builtin_amdgcn_mfma_f32_16x16x32_bf16(a,b,c,0,0,0)
#define MFMA_F16(a,b,c) __builtin_amdgcn_mfma_f32_16x16x32_f16(a,b,c,0,0,0)

#define BSTRIDE 516   // f32 elems per buf row (bank-shift 4)
#define PSTRIDE 520   // f16 elems per P row  (bank-shift 4, 16B-aligned rows)

// ---------- helpers ----------
__device__ __forceinline__ unsigned mtu(float f){
  unsigned u = __float_as_uint(f);
  return (u & 0x80000000u) ? ~u : (u | 0x80000000u);
}
__device__ __forceinline__ float umt(unsigned u){
  return __uint_as_float((u & 0x80000000u) ? (u & 0x7fffffffu) : ~u);
}
__device__ __forceinline__ int wsum_i(int v){
  #pragma unroll
  for (int m=1;m<64;m<<=1) v += __shfl_xor(v,m,64);
  return v;
}
__device__ __forceinline__ float wsum_f(float v){
  #pragma unroll
  for (int m=1;m<64;m<<=1) v += __shfl_xor(v,m,64);
  return v;
}
__device__ __forceinline__ unsigned wmax_u(unsigned v){
  #pragma unroll
  for (int m=1;m<64;m<<=1){ unsigned o=(unsigned)__shfl_xor((int)v,m,64); v = o>v?o:v; }
  return v;
}
__device__ __forceinline__ unsigned wmin_u(unsigned v){
  #pragma unroll
  for (int m=1;m<64;m<<=1){ unsigned o=(unsigned)__shfl_xor((int)v,m,64); v = o<v?o:v; }
  return v;
}
__device__ __forceinline__ ushort_t f2bf(float f){       // RNE f32->bf16
  unsigned u = __float_as_uint(f);
  return (ushort_t)((u + 0x7fffu + ((u>>16)&1u)) >> 16);
}
__device__ __forceinline__ float bf2f(ushort_t u){
  return __uint_as_float(((unsigned)u) << 16);
}
__device__ __forceinline__ short8 ldb8(const ushort_t* p){ return *(const short8*)p; }

// ---------- K0: fp32 -> bf16 hi/lo for x and W(q|k|v) ----------
__global__ void cvt_kernel(const float* __restrict__ x,
                           const float* __restrict__ Wq, const float* __restrict__ Wk,
                           const float* __restrict__ Wv,
                           ushort_t* __restrict__ xh, ushort_t* __restrict__ xl,
                           ushort_t* __restrict__ wh, ushort_t* __restrict__ wl){
  const int bid = blockIdx.x, tid = threadIdx.x;
  const float* src; ushort_t *dh, *dl; size_t base;
  if (bid < 2048){                       // x: 8192*256 elements
    base = ((size_t)bid*256 + tid)*4;
    src = &x[base]; dh = xh; dl = xl;
  } else {                               // W: 768*256 elements
    base = ((size_t)(bid-2048)*256 + tid)*4;
    const int row = (int)(base >> 8);
    src = row<256 ? &Wq[base] : (row<512 ? &Wk[base-65536] : &Wv[base-131072]);
    dh = wh; dl = wl;
  }
  float4 v = *(const float4*)src;
  short4v hv, lv;
  ushort_t h;
  h=f2bf(v.x); hv.x=(short)h; lv.x=(short)f2bf(v.x-bf2f(h));
  h=f2bf(v.y); hv.y=(short)h; lv.y=(short)f2bf(v.y-bf2f(h));
  h=f2bf(v.z); hv.z=(short)h; lv.z=(short)f2bf(v.z-bf2f(h));
  h=f2bf(v.w); hv.w=(short)h; lv.w=(short)f2bf(v.w-bf2f(h));
  *(short4v*)&dh[base] = hv;
  *(short4v*)&dl[base] = lv;
}

// ---------- K1a: per-(b,chunk) column sums of x ----------
__global__ void xpart_kernel(const float* __restrict__ x, float* __restrict__ xpart){
  const int ch = blockIdx.x, b = blockIdx.y, t = threadIdx.x;
  const float* xp = x + ((size_t)b*2048 + (size_t)ch*128)*256 + t;
  float s = 0.f;
  for (int i=0;i<128;i++) s += xp[(size_t)i*256];
  xpart[(size_t)(b*16+ch)*256 + t] = s;
}

// ---------- K1b: gate[b][256] (no sigmoid on the 256-d projection) ----------
__global__ void gate_kernel(const float* __restrict__ xpart,
                            const float* __restrict__ Wg, const float* __restrict__ bg,
                            const float* __restrict__ Wgp,const float* __restrict__ bgp,
                            float* __restrict__ gate_ws){
  __shared__ float xm[256];
  __shared__ float g16[16];
  const int t = threadIdx.x;
  for (int b=0;b<4;b++){
    float s = 0.f;
    for (int ch=0; ch<16; ch++) s += xpart[(size_t)(b*16+ch)*256 + t];
    xm[t] = s * (1.0f/2048.0f);
    __syncthreads();
    if (t < 16){
      float z = bg[t];
      for (int d=0; d<256; d++) z = fmaf(xm[d], Wg[t*256+d], z);
      g16[t] = 1.0f/(1.0f + __expf(-z));
    }
    __syncthreads();
    float z2 = bgp[t];
    #pragma unroll
    for (int j=0;j<16;j++) z2 = fmaf(g16[j], Wgp[t*16+j], z2);
    gate_ws[b*256 + t] = z2;
    __syncthreads();
  }
}

// ---------- K1c: fold distill+gate+out into per-batch M[k][j] and bias ----------
// out_row = att_row @ M_b + bo_b
// M_b[k][j] = sum_{i in grp(k)} g[i]*Wd[i&15][k&15]*Wo[j][i] + (1-g[k])*Wo[j][k]
// bo_b[j]  = bo[j] + sum_i g[i]*bd[i&15]*Wo[j][i]
// stored transposed for B-frags: mt[b][j][k]
__global__ void mprep_kernel(const float* __restrict__ Wd, const float* __restrict__ bd,
                             const float* __restrict__ Wo, const float* __restrict__ bo,
                             const float* __restrict__ gate_ws,
                             ushort_t* __restrict__ mt_h, ushort_t* __restrict__ mt_l,
                             float* __restrict__ bo_b){
  __shared__ float e[256][16];
  __shared__ float gs[256];
  const int b = blockIdx.x, j = threadIdx.x;
  gs[j] = gate_ws[b*256 + j];
  __syncthreads();
  for (int t = j; t < 4096; t += 256){
    const int k = t>>4, m = t&15;
    e[k][m] = gs[(k & ~15) + m] * Wd[m*16 + (k&15)];
  }
  __syncthreads();
  const float* worow = Wo + (size_t)j*256;
  for (int k=0;k<256;k++){
    float acc = (1.0f - gs[k]) * worow[k];
    const int g0 = k & ~15;
    #pragma unroll
    for (int m=0;m<16;m++) acc = fmaf(e[k][m], worow[g0+m], acc);
    const ushort_t hi = f2bf(acc);
    mt_h[((size_t)b*256 + j)*256 + k] = hi;
    mt_l[((size_t)b*256 + j)*256 + k] = f2bf(acc - bf2f(hi));
  }
  float bacc = bo[j];
  for (int i=0;i<256;i++) bacc = fmaf(gs[i]*bd[i&15], worow[i], bacc);
  bo_b[b*256 + j] = bacc;
}

// ---------- K2: QKV projection, split-bf16 MFMA (4 terms) ----------
__global__ __launch_bounds__(256) void qkv_mfma(
    const ushort_t* __restrict__ xh, const ushort_t* __restrict__ xl,
    const ushort_t* __restrict__ wh, const ushort_t* __restrict__ wl,
    const float* __restrict__ bq, const float* __restrict__ bk, const float* __restrict__ bv,
    ushort_t* __restrict__ qh, ushort_t* __restrict__ ql,
    ushort_t* __restrict__ kh, ushort_t* __restrict__ kl,
    _Float16* __restrict__ vt){
  __shared__ _Float16 trans[64][72];            // V-tile transpose staging
  const int m0 = blockIdx.x*64, n0g = blockIdx.y*64;
  const int sect = n0g >> 8, nloc0 = n0g & 255;
  const int tid = threadIdx.x, w = tid>>6, ln = tid&63;
  const int lm = ln&15, lko = (ln>>4)*8;
  const int arow = m0 + w*16 + lm;

  floatx4 acc[4];
  #pragma unroll
  for (int nt=0;nt<4;nt++){ floatx4 z = {0.f,0.f,0.f,0.f}; acc[nt] = z; }

  for (int k0=0;k0<256;k0+=32){
    short8 a_h = ldb8(&xh[(size_t)arow*256 + k0 + lko]);
    short8 a_l = ldb8(&xl[(size_t)arow*256 + k0 + lko]);
    #pragma unroll
    for (int nt=0;nt<4;nt++){
      const size_t boff = (size_t)(n0g + nt*16 + lm)*256 + k0 + lko;
      short8 b_h = ldb8(&wh[boff]);
      short8 b_l = ldb8(&wl[boff]);
      acc[nt] = MFMA_BF(a_h,b_h,acc[nt]);
      acc[nt] = MFMA_BF(a_h,b_l,acc[nt]);
      acc[nt] = MFMA_BF(a_l,b_h,acc[nt]);
      acc[nt] = MFMA_BF(a_l,b_l,acc[nt]);
    }
  }

  const float* bias = (sect==0)?bq:((sect==1)?bk:bv);
  const int bidx = m0 >> 11;
  #pragma unroll
  for (int nt=0;nt<4;nt++){
    #pragma unroll
    for (int r=0;r<4;r++){
      const int row = w*16 + (ln>>4)*4 + r;          // local row in [0,64)
      const int f = nloc0 + nt*16 + lm;
      const float val = acc[nt][r] + bias[f];
      if (sect == 2){
        trans[nt*16+lm][row] = (_Float16)val;
      } else {
        const int hh = f>>6, hd = f&63;
        const size_t idx = (size_t)((bidx*4+hh)*2048 + (m0&2047) + row)*64 + hd;
        const ushort_t hi = f2bf(val);
        const ushort_t lo = f2bf(val - bf2f(hi));
        if (sect==0){ qh[idx]=hi; ql[idx]=lo; }
        else        { kh[idx]=hi; kl[idx]=lo; }
      }
    }
  }
  if (sect == 2){
    __syncthreads();
    const int d = tid>>2, sc = (tid&3)*16;
    const int bh_ = bidx*4 + (nloc0>>6);
    half8 v0 = *(half8*)&trans[d][sc];
    half8 v1 = *(half8*)&trans[d][sc+8];
    _Float16* dst = vt + ((size_t)bh_*64 + d)*2048 + (m0&2047) + sc;
    *(half8*)dst = v0;
    *(half8*)(dst+8) = v1;
  }
}

// ---------- K3: sparse attention (MFMA scores, exact quantile, MFMA PV) ----------
__global__ __launch_bounds__(512,4) void attn_kernel(
    const ushort_t* __restrict__ qh, const ushort_t* __restrict__ ql,
    const ushort_t* __restrict__ kh, const ushort_t* __restrict__ kl,
    const _Float16* __restrict__ vt,
    ushort_t* __restrict__ att_h, ushort_t* __restrict__ att_l){
  __shared__ float buf[16*BSTRIDE];          // 33024 B: f32 scores / f16 P / osum tail
  __shared__ float zrow[16];
  __shared__ unsigned cand[16][64];
  _Float16* Pb = (_Float16*)buf;             // [16][PSTRIDE] f16 = 16640 B
  float* osum = buf + (16*BSTRIDE - 2048);   // last 8 KB (disjoint from Pb)

  const int bh = blockIdx.y;
  const int q0 = blockIdx.x * 16;
  const int tid = threadIdx.x;
  const int w = tid>>6, ln = tid&63;
  const int lm = ln&15, lk = (ln>>4)*8;
  const int qa = 2*w, qb = 2*w+1;

  const ushort_t* Qh = qh + ((size_t)bh*2048 + q0)*64;
  const ushort_t* Ql = ql + ((size_t)bh*2048 + q0)*64;
  const ushort_t* Kh = kh + (size_t)bh*2048*64;
  const ushort_t* Kl = kl + (size_t)bh*2048*64;

  unsigned su0[32], su1[32];

  // ----- phase A: scores. chunk c covers contiguous keys [c*512,(c+1)*512) -----
  #pragma unroll
  for (int c=0;c<4;c++){
    short8 ah0 = ldb8(Qh + lm*64 + lk);
    short8 ah1 = ldb8(Qh + lm*64 + 32 + lk);
    short8 al0 = ldb8(Ql + lm*64 + lk);
    short8 al1 = ldb8(Ql + lm*64 + 32 + lk);
    floatx4 accq[4];
    #pragma unroll
    for (int tl=0;tl<4;tl++){
      const int krow = c*512 + w*64 + tl*16 + lm;
      short8 bh0 = ldb8(Kh + (size_t)krow*64 + lk);
      short8 bh1 = ldb8(Kh + (size_t)krow*64 + 32 + lk);
      short8 bl0 = ldb8(Kl + (size_t)krow*64 + lk);
      short8 bl1 = ldb8(Kl + (size_t)krow*64 + 32 + lk);
      floatx4 a = {0.f,0.f,0.f,0.f};
      a = MFMA_BF(ah0,bh0,a); a = MFMA_BF(ah1,bh1,a);
      a = MFMA_BF(al0,bh0,a); a = MFMA_BF(al1,bh1,a);
      a = MFMA_BF(ah0,bl0,a); a = MFMA_BF(ah1,bl1,a);
      a = MFMA_BF(al0,bl0,a); a = MFMA_BF(al1,bl1,a);
      accq[tl] = a;
    }
    __syncthreads();
    const int wr = (ln>>4)*4;
    #pragma unroll
    for (int tl=0;tl<4;tl++){
      const int col = w*64 + tl*16 + lm;
      buf[(wr+0)*BSTRIDE + col] = accq[tl][0]*0.125f;
      buf[(wr+1)*BSTRIDE + col] = accq[tl][1]*0.125f;
      buf[(wr+2)*BSTRIDE + col] = accq[tl][2]*0.125f;
      buf[(wr+3)*BSTRIDE + col] = accq[tl][3]*0.125f;
    }
    __syncthreads();
    float4 ra0 = *(const float4*)&buf[qa*BSTRIDE + 4*ln];
    float4 ra1 = *(const float4*)&buf[qa*BSTRIDE + 256 + 4*ln];
    float4 rb0 = *(const float4*)&buf[qb*BSTRIDE + 4*ln];
    float4 rb1 = *(const float4*)&buf[qb*BSTRIDE + 256 + 4*ln];
    const int o = c*8;
    su0[o+0]=mtu(ra0.x); su0[o+1]=mtu(ra0.y); su0[o+2]=mtu(ra0.z); su0[o+3]=mtu(ra0.w);
    su0[o+4]=mtu(ra1.x); su0[o+5]=mtu(ra1.y); su0[o+6]=mtu(ra1.z); su0[o+7]=mtu(ra1.w);
    su1[o+0]=mtu(rb0.x); su1[o+1]=mtu(rb0.y); su1[o+2]=mtu(rb0.z); su1[o+3]=mtu(rb0.w);
    su1[o+4]=mtu(rb1.x); su1[o+5]=mtu(rb1.y); su1[o+6]=mtu(rb1.z); su1[o+7]=mtu(rb1.w);
  }
  // su idx i (c=i>>3, m=i&7) -> key = c*512 + ((m&4)?256:0) + ln*4 + (m&3)

  // ----- level-1: bisect top 16 bits (both rows packed) -----
  unsigned p0=0, p1=0;
  #pragma unroll 1
  for (int bit=31; bit>=16; --bit){
    const unsigned c0 = p0 | (1u<<bit);
    const unsigned c1 = p1 | (1u<<bit);
    int n0=0, n1=0;
    #pragma unroll
    for (int i=0;i<32;i++){
      n0 += (su0[i] >= c0) ? 1 : 0;
      n1 += (su1[i] >= c1) ? 1 : 0;
    }
    int packed = n0 | (n1<<16);
    packed = wsum_i(packed);
    if ((packed & 0xffff) >= 206) p0 = c0;
    if ((packed >> 16)    >= 206) p1 = c1;
  }

  // ----- per-row exact v205/v204 -> threshold -----
  const unsigned long long lmask = (1ull << ln) - 1ull;
  float thrv[2], mxv[2];
  #pragma unroll
  for (int rr=0; rr<2; rr++){
    const int q = w*2 + rr;
    const unsigned p = rr ? p1 : p0;
    const unsigned hiu = p + 0x10000u;
    int above = 0, nc = 0;
    unsigned mnab = 0xffffffffu, mx = 0;
    #pragma unroll
    for (int i=0;i<32;i++){
      const unsigned u = rr ? su1[i] : su0[i];
      mx = (u > mx) ? u : mx;
      const bool ab = (u >= hiu);
      above += ab ? 1 : 0;
      if (ab && u < mnab) mnab = u;
      const bool cd = (u >= p) && !ab;
      const unsigned long long bal = __ballot(cd);
      if (cd){
        const int pos = nc + (int)__popcll(bal & lmask);
        if (pos < 64) cand[q][pos] = u;
      }
      nc += (int)__popcll(bal);
    }
    above = wsum_i(above);
    mnab = wmin_u(mnab);
    mx = wmax_u(mx);

    unsigned v205u, v204u;
    if (nc <= 64){
      const int j = 206 - above;
      const unsigned cv = (ln < nc) ? cand[q][ln] : 0u;
      unsigned v = p;
      #pragma unroll 1
      for (int bit=15; bit>=0; --bit){
        const unsigned c = v | (1u<<bit);
        int n = (cv >= c) ? 1 : 0;
        n = wsum_i(n);
        if (n >= j) v = c;
      }
      v205u = v;
      int cgtc = (cv > v) ? 1 : 0;
      unsigned mnc = (cv > v) ? cv : 0xffffffffu;
      cgtc = wsum_i(cgtc);
      mnc = wmin_u(mnc);
      const int cgt = above + cgtc;
      v204u = (cgt == 205) ? ((cgtc > 0) ? mnc : mnab) : v205u;
    } else {
      unsigned v = p;
      #pragma unroll 1
      for (int bit=15; bit>=0; --bit){
        const unsigned c = v | (1u<<bit);
        int n = 0;
        #pragma unroll
        for (int i=0;i<32;i++) n += ((rr ? su1[i] : su0[i]) >= c) ? 1 : 0;
        n = wsum_i(n);
        if (n >= 206) v = c;
      }
      v205u = v;
      int cgt = 0; unsigned mn = 0xffffffffu;
      #pragma unroll
      for (int i=0;i<32;i++){
        const unsigned u = rr ? su1[i] : su0[i];
        const bool gt = (u > v);
        cgt += gt ? 1 : 0;
        if (gt && u < mn) mn = u;
      }
      cgt = wsum_i(cgt);
      mn = wmin_u(mn);
      v204u = (cgt == 205) ? mn : v205u;
    }
    const float aa = umt(v205u), bb = umt(v204u);
    thrv[rr] = (float)((double)aa + 0.3*((double)bb - (double)aa));
    mxv[rr]  = umt(mx);
  }

  // ----- phase B: masked-softmax P chunks (f16, dense) + MFMA PV -----
  float zacc0 = 0.f, zacc1 = 0.f;
  floatx4 opv = {0.f,0.f,0.f,0.f};
  const int nt = w & 3;
  const int kh8 = (w>>2)*8;
  const _Float16* Vtb = vt + (size_t)bh*64*2048 + ((size_t)(nt*16+lm))*2048;

  #pragma unroll 1
  for (int c=0;c<4;c++){
    __syncthreads();                           // P buffer free
    {
      half4 s0, s1;
      float zl = 0.f;
      #pragma unroll
      for (int m=0;m<8;m++){
        const float s = umt(su0[c*8+m]);
        const float pr = (s >= thrv[0]) ? __expf(s - mxv[0]) : 0.f;
        zl += pr;
        if (m<4) s0[m] = (_Float16)pr; else s1[m-4] = (_Float16)pr;
      }
      zacc0 += zl;
      *(half4*)&Pb[qa*PSTRIDE + 4*ln]       = s0;
      *(half4*)&Pb[qa*PSTRIDE + 256 + 4*ln] = s1;
    }
    {
      half4 s0, s1;
      float zl = 0.f;
      #pragma unroll
      for (int m=0;m<8;m++){
        const float s = umt(su1[c*8+m]);
        const float pr = (s >= thrv[1]) ? __expf(s - mxv[1]) : 0.f;
        zl += pr;
        if (m<4) s0[m] = (_Float16)pr; else s1[m-4] = (_Float16)pr;
      }
      zacc1 += zl;
      *(half4*)&Pb[qb*PSTRIDE + 4*ln]       = s0;
      *(half4*)&Pb[qb*PSTRIDE + 256 + 4*ln] = s1;
    }
    __syncthreads();                           // P visible
    #pragma unroll
    for (int kk2=0; kk2<8; kk2++){
      const int kk = kh8 + kk2;
      half8 a = *(half8*)&Pb[lm*PSTRIDE + kk*32 + lk];
      half8 b = *(const half8*)&Vtb[c*512 + kk*32 + lk];
      opv = MFMA_F16(a,b,opv);
    }
  }

  const float Z0 = wsum_f(zacc0);
  const float Z1 = wsum_f(zacc1);
  if (ln == 0){ zrow[qa] = Z0; zrow[qb] = Z1; }
  __syncthreads();
  #pragma unroll
  for (int r=0;r<4;r++)
    osum[w*256 + ((ln>>4)*4 + r)*16 + lm] = opv[r];
  __syncthreads();
  if (w < 4){
    const int b_ = bh>>2, h = bh&3;
    #pragma unroll
    for (int r=0;r<4;r++){
      const int row = (ln>>4)*4 + r;
      float v = osum[w*256 + row*16 + lm] + osum[(w+4)*256 + row*16 + lm];
      v /= zrow[row];
      const ushort_t hi = f2bf(v);
      const ushort_t lo = f2bf(v - bf2f(hi));
      const size_t oi = ((size_t)(b_*2048 + q0 + row))*256 + h*64 + w*16 + lm;
      att_h[oi] = hi;
      att_l[oi] = lo;
    }
  }
}

// ---------- K4: out = att @ M_b + bo_b, split-bf16 MFMA (3 terms) ----------
__global__ __launch_bounds__(256) void out_mfma(
    const ushort_t* __restrict__ ah_, const ushort_t* __restrict__ al_,
    const ushort_t* __restrict__ mh_, const ushort_t* __restrict__ ml_,
    const float* __restrict__ bo_b, float* __restrict__ out){
  const int bz = blockIdx.z;
  const int m0 = blockIdx.x*64, n0 = blockIdx.y*64;
  const int tid = threadIdx.x, w = tid>>6, ln = tid&63;
  const int lm = ln&15, lko = (ln>>4)*8;
  const size_t arow = (size_t)bz*2048 + m0 + w*16 + lm;

  floatx4 acc[4];
  #pragma unroll
  for (int nt=0;nt<4;nt++){ floatx4 z = {0.f,0.f,0.f,0.f}; acc[nt] = z; }

  for (int k0=0;k0<256;k0+=32){
    short8 a_h = ldb8(&ah_[arow*256 + k0 + lko]);
    short8 a_l = ldb8(&al_[arow*256 + k0 + lko]);
    #pragma unroll
    for (int nt=0;nt<4;nt++){
      const size_t boff = ((size_t)bz*256 + n0 + nt*16 + lm)*256 + k0 + lko;
      short8 b_h = ldb8(&mh_[boff]);
      short8 b_l = ldb8(&ml_[boff]);
      acc[nt] = MFMA_BF(a_h,b_h,acc[nt]);
      acc[nt] = MFMA_BF(a_h,b_l,acc[nt]);
      acc[nt] = MFMA_BF(a_l,b_h,acc[nt]);
    }
  }
  #pragma unroll
  for (int nt=0;nt<4;nt++){
    #pragma unroll
    for (int r=0;r<4;r++){
      const int row = m0 + w*16 + (ln>>4)*4 + r;
      const int col = n0 + nt*16 + lm;
      out[((size_t)bz*2048 + row)*256 + col] = acc[nt][r] + bo_b[bz*256 + col];
    }
  }
}

// ---------- launch ----------
extern "C" void kernel_launch(void* const* d_in, const int* in_sizes, int n_in,
                              void* d_out, int out_size, void* d_ws, size_t ws_size,
                              hipStream_t stream) {
  const float* x   = (const float*)d_in[0];
  const float* Wq  = (const float*)d_in[1];  const float* bq  = (const float*)d_in[2];
  const float* Wk  = (const float*)d_in[3];  const float* bk  = (const float*)d_in[4];
  const float* Wv  = (const float*)d_in[5];  const float* bv  = (const float*)d_in[6];
  const float* Wd  = (const float*)d_in[7];  const float* bd  = (const float*)d_in[8];
  const float* Wg  = (const float*)d_in[9];  const float* bg  = (const float*)d_in[10];
  const float* Wgp = (const float*)d_in[11]; const float* bgp = (const float*)d_in[12];
  const float* Wo  = (const float*)d_in[13]; const float* bo  = (const float*)d_in[14];

  char* base = (char*)d_ws;
  const size_t MB = 1024*1024;
  ushort_t* xh   = (ushort_t*)(base + 0*MB);      // 4 MB
  ushort_t* xl   = (ushort_t*)(base + 4*MB);      // 4 MB
  ushort_t* wh   = (ushort_t*)(base + 8*MB);      // 384 KB
  ushort_t* wl   = (ushort_t*)(base + 8*MB + 512*1024);
  ushort_t* qh   = (ushort_t*)(base + 9*MB);      // 4 MB
  ushort_t* ql   = (ushort_t*)(base + 13*MB);     // 4 MB
  ushort_t* kh   = (ushort_t*)(base + 17*MB);     // 4 MB
  ushort_t* kl   = (ushort_t*)(base + 21*MB);     // 4 MB
  _Float16* vt   = (_Float16*)(base + 25*MB);     // 4 MB
  ushort_t* atth = (ushort_t*)(base + 29*MB);     // 4 MB
  ushort_t* attl = (ushort_t*)(base + 33*MB);     // 4 MB
  ushort_t* mt_h = (ushort_t*)(base + 37*MB);     // 512 KB
  ushort_t* mt_l = (ushort_t*)(base + 37*MB + 512*1024);
  float* bo_b    = (float*)(base + 38*MB);        // 4 KB
  float* gate_ws = (float*)(base + 38*MB + 4096);
  float* xpart   = (float*)(base + 38*MB + 8192); // 64 KB

  cvt_kernel<<<2240, 256, 0, stream>>>(x, Wq, Wk, Wv, xh, xl, wh, wl);
  xpart_kernel<<<dim3(16,4), 256, 0, stream>>>(x, xpart);
  gate_kernel<<<1, 256, 0, stream>>>(xpart, Wg, bg, Wgp, bgp, gate_ws);
  mprep_kernel<<<4, 256, 0, stream>>>(Wd, bd, Wo, bo, gate_ws, mt_h, mt_l, bo_b);
  qkv_mfma<<<dim3(128,12), 256, 0, stream>>>(xh, xl, wh, wl, bq, bk, bv,
                                             qh, ql, kh, kl, vt);
  attn_kernel<<<dim3(128,16), 512, 0, stream>>>(qh, ql, kh, kl, vt, atth, attl);
  out_mfma<<<dim3(32,4,4), 256, 0, stream>>>(atth, attl, mt_h, mt_l, bo_b, (float*)d_out);
}